// Round 4
// baseline (1608.355 us; speedup 1.0000x reference)
//
#include <hip/hip_runtime.h>
#include <hip/hip_bf16.h>

#define NN     10000
#define HEADS  8
#define HID    64
#define ODIM   5000
#define NE     160000
#define ET     170000   // NE + NN self-loops
#define NEG    0.2f

// -------- edge_index storage-format detection (int32 vs int64 words) --------
// int64 storage => odd 32-bit words are hi words of ids < 1e4 -> all zero.
// int32 storage => odd words are uniform ids in [0,10000): P(1024 zeros)~1e-4096.
__global__ void k_detect(const int* __restrict__ ei, int* __restrict__ flag) {
    __shared__ int nz;
    if (threadIdx.x == 0) nz = 0;
    __syncthreads();
    if (ei[2 * threadIdx.x + 1] != 0) atomicAdd(&nz, 1);
    __syncthreads();
    if (threadIdx.x == 0) *flag = (nz == 0) ? 1 : 0;
}
__device__ __forceinline__ int ld_idx(const int* ei, int k, int mode) {
    return mode ? ei[2 * k] : ei[k];   // little-endian lo word carries the id
}

// ---------------- CSR build (by dst) ----------------
__global__ void k_deg_init(int* __restrict__ deg) {
    int i = blockIdx.x * blockDim.x + threadIdx.x;
    if (i < NN) deg[i] = 1;   // self-loop
}
__global__ void k_hist(const int* __restrict__ ei, const int* __restrict__ flag,
                       int* __restrict__ deg) {
    int e = blockIdx.x * blockDim.x + threadIdx.x;
    if (e < NE) atomicAdd(&deg[ld_idx(ei, NE + e, *flag)], 1);
}
__global__ void k_scan(const int* __restrict__ deg, int* __restrict__ rowptr,
                       int* __restrict__ cursor) {
    __shared__ int sd[1024];
    __shared__ int carry;
    int t = threadIdx.x;
    if (t == 0) carry = 0;
    __syncthreads();
    for (int base = 0; base < NN; base += 1024) {
        int i = base + t;
        int v = (i < NN) ? deg[i] : 0;
        sd[t] = v;
        __syncthreads();
        for (int off = 1; off < 1024; off <<= 1) {
            int x = (t >= off) ? sd[t - off] : 0;
            __syncthreads();
            sd[t] += x;
            __syncthreads();
        }
        if (i < NN) { int ex = carry + sd[t] - v; rowptr[i] = ex; cursor[i] = ex; }
        __syncthreads();
        if (t == 0) carry += sd[1023];
        __syncthreads();
    }
    if (t == 0) rowptr[NN] = carry;
}
__global__ void k_scatter(const int* __restrict__ ei, const int* __restrict__ flag,
                          int* __restrict__ cursor, int* __restrict__ csr) {
    int e = blockIdx.x * blockDim.x + threadIdx.x;
    if (e < NE) {
        int mode = *flag;
        int d = ld_idx(ei, NE + e, mode);
        int pos = atomicAdd(&cursor[d], 1);
        csr[pos] = ld_idx(ei, e, mode);
    } else if (e < ET) {
        int n = e - NE;
        int pos = atomicAdd(&cursor[n], 1);
        csr[pos] = n;   // self-loop src == dst
    }
}

// ------- C[M,Ndim] = A[M,K] * W[Ndim,K]^T + bias  (all fp32, fp32 out) -------
__global__ void __launch_bounds__(256) k_gemm_nt(
    const float* __restrict__ A, const float* __restrict__ W,
    const float* __restrict__ bias, float* __restrict__ C,
    int M, int Ndim, int K) {
    __shared__ float As[32][64];
    __shared__ float Ws[32][64];
    int t = threadIdx.x;
    int m0 = blockIdx.x * 64, n0 = blockIdx.y * 64;
    int lm = t >> 2;
    int kc = (t & 3) * 8;
    int tx = t & 15, ty = t >> 4;
    int rowA = m0 + lm;
    int rowW = n0 + lm;
    float acc[4][4] = {};
    for (int kt = 0; kt < K; kt += 32) {
        float av[8];
        if (rowA < M) {
            const float* ap = A + (size_t)rowA * K + kt + kc;
            float4 p0 = *(const float4*)ap;
            float4 p1 = *(const float4*)(ap + 4);
            av[0] = p0.x; av[1] = p0.y; av[2] = p0.z; av[3] = p0.w;
            av[4] = p1.x; av[5] = p1.y; av[6] = p1.z; av[7] = p1.w;
        } else {
            #pragma unroll
            for (int j = 0; j < 8; j++) av[j] = 0.f;
        }
        const float* wp = W + (size_t)rowW * K + kt + kc;
        float4 q0 = *(const float4*)wp;
        float4 q1 = *(const float4*)(wp + 4);
        float wv[8] = {q0.x, q0.y, q0.z, q0.w, q1.x, q1.y, q1.z, q1.w};
        #pragma unroll
        for (int j = 0; j < 8; j++) As[kc + j][lm] = av[j];
        #pragma unroll
        for (int j = 0; j < 8; j++) Ws[kc + j][lm] = wv[j];
        __syncthreads();
        #pragma unroll
        for (int k = 0; k < 32; k++) {
            float4 a4 = *(const float4*)&As[k][ty * 4];
            float4 b4 = *(const float4*)&Ws[k][tx * 4];
            float aa[4] = {a4.x, a4.y, a4.z, a4.w};
            float bb[4] = {b4.x, b4.y, b4.z, b4.w};
            #pragma unroll
            for (int i = 0; i < 4; i++)
                #pragma unroll
                for (int j = 0; j < 4; j++)
                    acc[i][j] = fmaf(aa[i], bb[j], acc[i][j]);
        }
        __syncthreads();
    }
    int col0 = n0 + tx * 4;
    float4 bv = *(const float4*)&bias[col0];
    #pragma unroll
    for (int i = 0; i < 4; i++) {
        int r = m0 + ty * 4 + i;
        if (r < M) {
            float4 o = make_float4(acc[i][0] + bv.x, acc[i][1] + bv.y,
                                   acc[i][2] + bv.z, acc[i][3] + bv.w);
            *(float4*)&C[(size_t)r * Ndim + col0] = o;
        }
    }
}

// ------- fused GATv2 layer 1: one wave per node, online softmax -------
__global__ void __launch_bounds__(256) k_gat1(
    const float* __restrict__ xl, const float* __restrict__ xr,
    const float* __restrict__ att, const float* __restrict__ bias,
    const int* __restrict__ rowptr, const int* __restrict__ csr,
    float* __restrict__ out) {
    int wid = (blockIdx.x * blockDim.x + threadIdx.x) >> 6;
    int lane = threadIdx.x & 63;
    if (wid >= NN) return;
    int n = wid;
    float xrv[HEADS], atv[HEADS], acc[HEADS], lsum[HEADS], mmax[HEADS];
    #pragma unroll
    for (int h = 0; h < HEADS; h++) {
        int c = h * 64 + lane;
        xrv[h] = xr[(size_t)n * 512 + c];
        atv[h] = att[c];
        acc[h] = 0.f; lsum[h] = 0.f; mmax[h] = -1e30f;
    }
    int p0 = rowptr[n], p1 = rowptr[n + 1];
    for (int p = p0; p < p1; p++) {
        int s = csr[p];
        const float* xlrow = xl + (size_t)s * 512;
        float xs[HEADS], sc[HEADS];
        #pragma unroll
        for (int h = 0; h < HEADS; h++) {
            xs[h] = xlrow[h * 64 + lane];
            float v = xs[h] + xrv[h];
            v = (v > 0.f) ? v : NEG * v;
            sc[h] = v * atv[h];
        }
        #pragma unroll
        for (int h = 0; h < HEADS; h++) {
            float ssum = sc[h];
            #pragma unroll
            for (int off = 32; off > 0; off >>= 1)
                ssum += __shfl_xor(ssum, off, 64);
            sc[h] = ssum;
        }
        #pragma unroll
        for (int h = 0; h < HEADS; h++) {
            float mn = fmaxf(mmax[h], sc[h]);
            float scale = __expf(mmax[h] - mn);
            float pe = __expf(sc[h] - mn);
            acc[h] = acc[h] * scale + pe * xs[h];
            lsum[h] = lsum[h] * scale + pe;
            mmax[h] = mn;
        }
    }
    #pragma unroll
    for (int h = 0; h < HEADS; h++) {
        int c = h * 64 + lane;
        float o = acc[h] / (lsum[h] + 1e-16f) + bias[c];
        out[(size_t)n * 512 + c] = (o > 0.f) ? o : 0.f;   // ReLU after layer 1
    }
}

// ------- fused GATv2 layer 2 (1 head, 64 ch): one wave per node -------
__global__ void __launch_bounds__(256) k_gat2(
    const float* __restrict__ xl, const float* __restrict__ xr,
    const float* __restrict__ att, const float* __restrict__ bias,
    const int* __restrict__ rowptr, const int* __restrict__ csr,
    float* __restrict__ out) {
    int wid = (blockIdx.x * blockDim.x + threadIdx.x) >> 6;
    int lane = threadIdx.x & 63;
    if (wid >= NN) return;
    int n = wid;
    float xrv = xr[(size_t)n * 64 + lane];
    float atv = att[lane];
    float acc = 0.f, lsum = 0.f, mmax = -1e30f;
    int p0 = rowptr[n], p1 = rowptr[n + 1];
    for (int p = p0; p < p1; p++) {
        int s = csr[p];
        float xs = xl[(size_t)s * 64 + lane];
        float v = xs + xrv;
        v = (v > 0.f) ? v : NEG * v;
        float sc = v * atv;
        #pragma unroll
        for (int off = 32; off > 0; off >>= 1)
            sc += __shfl_xor(sc, off, 64);
        float mn = fmaxf(mmax, sc);
        float scale = __expf(mmax - mn);
        float pe = __expf(sc - mn);
        acc = acc * scale + pe * xs;
        lsum = lsum * scale + pe;
        mmax = mn;
    }
    float o = acc / (lsum + 1e-16f) + bias[lane];
    out[(size_t)n * 64 + lane] = (o > 0.f) ? o : 0.f;   // ReLU after layer 2
}

// --- FC: out[10000,5000](fp32) = h2[10000,64] * fc_w[5000,64]^T + fc_b ---
__global__ void __launch_bounds__(256) k_fc(
    const float* __restrict__ A, const float* __restrict__ W,
    const float* __restrict__ bias, float* __restrict__ C) {
    __shared__ float As[64][64];
    __shared__ float Ws[64][64];
    int t = threadIdx.x;
    int m0 = blockIdx.x * 64, n0 = blockIdx.y * 64;
    int lm = t >> 2, kc = (t & 3) * 16;
    int row = m0 + lm;
    #pragma unroll
    for (int q = 0; q < 4; q++) {
        float4 pv = make_float4(0.f, 0.f, 0.f, 0.f);
        if (row < NN) pv = *(const float4*)(A + (size_t)row * 64 + kc + q * 4);
        As[kc + q * 4 + 0][lm] = pv.x;
        As[kc + q * 4 + 1][lm] = pv.y;
        As[kc + q * 4 + 2][lm] = pv.z;
        As[kc + q * 4 + 3][lm] = pv.w;
    }
    int coln = n0 + lm;
    #pragma unroll
    for (int q = 0; q < 4; q++) {
        float4 pv = make_float4(0.f, 0.f, 0.f, 0.f);
        if (coln < ODIM) pv = *(const float4*)(W + (size_t)coln * 64 + kc + q * 4);
        Ws[kc + q * 4 + 0][lm] = pv.x;
        Ws[kc + q * 4 + 1][lm] = pv.y;
        Ws[kc + q * 4 + 2][lm] = pv.z;
        Ws[kc + q * 4 + 3][lm] = pv.w;
    }
    __syncthreads();
    int tx = t & 15, ty = t >> 4;
    float acc[4][4] = {};
    #pragma unroll
    for (int k = 0; k < 64; k++) {
        float4 a4 = *(const float4*)&As[k][ty * 4];
        float4 b4 = *(const float4*)&Ws[k][tx * 4];
        float aa[4] = {a4.x, a4.y, a4.z, a4.w};
        float bb[4] = {b4.x, b4.y, b4.z, b4.w};
        #pragma unroll
        for (int i = 0; i < 4; i++)
            #pragma unroll
            for (int j = 0; j < 4; j++)
                acc[i][j] = fmaf(aa[i], bb[j], acc[i][j]);
    }
    int col0 = n0 + tx * 4;
    if (col0 < ODIM) {    // ODIM % 4 == 0 -> 4-wide chunk fully valid or fully out
        float4 bv = *(const float4*)&bias[col0];
        #pragma unroll
        for (int i = 0; i < 4; i++) {
            int r = m0 + ty * 4 + i;
            if (r < NN) {
                // fp32 output: row stride 5000*4 B == 0 mod 16, col0 % 4 == 0
                // -> float4 store always 16B-aligned.
                float4 o = make_float4(acc[i][0] + bv.x, acc[i][1] + bv.y,
                                       acc[i][2] + bv.z, acc[i][3] + bv.w);
                *(float4*)&C[(size_t)r * ODIM + col0] = o;
            }
        }
    }
}

extern "C" void kernel_launch(void* const* d_in, const int* in_sizes, int n_in,
                              void* d_out, int out_size, void* d_ws, size_t ws_size,
                              hipStream_t stream) {
    const float* x     = (const float*)d_in[0];
    const int*   ei    = (const int*)d_in[1];
    const float* W1l   = (const float*)d_in[2];
    const float* b1l   = (const float*)d_in[3];
    const float* W1r   = (const float*)d_in[4];
    const float* b1r   = (const float*)d_in[5];
    const float* att1  = (const float*)d_in[6];
    const float* bias1 = (const float*)d_in[7];
    const float* W2l   = (const float*)d_in[8];
    const float* b2l   = (const float*)d_in[9];
    const float* W2r   = (const float*)d_in[10];
    const float* b2r   = (const float*)d_in[11];
    const float* att2  = (const float*)d_in[12];
    const float* bias2 = (const float*)d_in[13];
    const float* fcw   = (const float*)d_in[14];
    const float* fcb   = (const float*)d_in[15];
    float* out = (float*)d_out;

    char* p = (char*)d_ws;
    auto carve = [&](size_t bytes) {
        void* r = (void*)p;
        p += (bytes + 255) & ~(size_t)255;
        return r;
    };
    // small arrays first, then the big float buffers; layer-2 buffers alias
    // the xl1 region (dead once k_gat1 finished). Peak ws ~= 62.3 MB.
    int* deg    = (int*)carve((size_t)NN * 4);
    int* rowptr = (int*)carve((size_t)(NN + 1) * 4);
    int* cursor = (int*)carve((size_t)NN * 4);
    int* csr    = (int*)carve((size_t)ET * 4);
    int* flag   = (int*)carve(256);
    float* xl1 = (float*)carve((size_t)NN * 512 * 4);
    float* xr1 = (float*)carve((size_t)NN * 512 * 4);
    float* h1  = (float*)carve((size_t)NN * 512 * 4);
    float* xl2 = xl1;                            // aliases: xl1/xr1 dead after k_gat1
    float* xr2 = xl1 + (size_t)NN * 64;
    float* h2  = xl1 + (size_t)NN * 128;

    // edge_index int32/int64 layout detection + CSR by destination
    k_detect<<<1, 1024, 0, stream>>>(ei, flag);
    k_deg_init<<<(NN + 255) / 256, 256, 0, stream>>>(deg);
    k_hist<<<(NE + 255) / 256, 256, 0, stream>>>(ei, flag, deg);
    k_scan<<<1, 1024, 0, stream>>>(deg, rowptr, cursor);
    k_scatter<<<(ET + 255) / 256, 256, 0, stream>>>(ei, flag, cursor, csr);

    // layer 1
    dim3 g1((NN + 63) / 64, 512 / 64);
    k_gemm_nt<<<g1, 256, 0, stream>>>(x, W1l, b1l, xl1, NN, 512, 512);
    k_gemm_nt<<<g1, 256, 0, stream>>>(x, W1r, b1r, xr1, NN, 512, 512);
    k_gat1<<<(NN * 64 + 255) / 256, 256, 0, stream>>>(xl1, xr1, att1, bias1, rowptr, csr, h1);

    // layer 2
    dim3 g2((NN + 63) / 64, 1);
    k_gemm_nt<<<g2, 256, 0, stream>>>(h1, W2l, b2l, xl2, NN, 64, 512);
    k_gemm_nt<<<g2, 256, 0, stream>>>(h1, W2r, b2r, xr2, NN, 64, 512);
    k_gat2<<<(NN * 64 + 255) / 256, 256, 0, stream>>>(xl2, xr2, att2, bias2, rowptr, csr, h2);

    // FC head
    dim3 g3((NN + 63) / 64, (ODIM + 63) / 64);
    k_fc<<<g3, 256, 0, stream>>>(h2, fcw, fcb, out);
}

// Round 5
// 728.585 us; speedup vs baseline: 2.2075x; 2.2075x over previous
//
#include <hip/hip_runtime.h>
#include <hip/hip_bf16.h>

#define NN     10000
#define HEADS  8
#define HID    64
#define ODIM   5000
#define NE     160000
#define ET     170000   // NE + NN self-loops
#define NEG    0.2f
#define WT_LD  5120     // padded leading dim of transposed fc_w

// -------- edge_index storage-format detection (int32 vs int64 words) --------
__global__ void k_detect(const int* __restrict__ ei, int* __restrict__ flag) {
    __shared__ int nz;
    if (threadIdx.x == 0) nz = 0;
    __syncthreads();
    if (ei[2 * threadIdx.x + 1] != 0) atomicAdd(&nz, 1);
    __syncthreads();
    if (threadIdx.x == 0) *flag = (nz == 0) ? 1 : 0;
}
__device__ __forceinline__ int ld_idx(const int* ei, int k, int mode) {
    return mode ? ei[2 * k] : ei[k];   // little-endian lo word carries the id
}

// ---------------- CSR build (by dst) ----------------
__global__ void k_deg_init(int* __restrict__ deg) {
    int i = blockIdx.x * blockDim.x + threadIdx.x;
    if (i < NN) deg[i] = 1;   // self-loop
}
__global__ void k_hist(const int* __restrict__ ei, const int* __restrict__ flag,
                       int* __restrict__ deg) {
    int e = blockIdx.x * blockDim.x + threadIdx.x;
    if (e < NE) atomicAdd(&deg[ld_idx(ei, NE + e, *flag)], 1);
}
__global__ void k_scan(const int* __restrict__ deg, int* __restrict__ rowptr,
                       int* __restrict__ cursor) {
    __shared__ int sd[1024];
    __shared__ int carry;
    int t = threadIdx.x;
    if (t == 0) carry = 0;
    __syncthreads();
    for (int base = 0; base < NN; base += 1024) {
        int i = base + t;
        int v = (i < NN) ? deg[i] : 0;
        sd[t] = v;
        __syncthreads();
        for (int off = 1; off < 1024; off <<= 1) {
            int x = (t >= off) ? sd[t - off] : 0;
            __syncthreads();
            sd[t] += x;
            __syncthreads();
        }
        if (i < NN) { int ex = carry + sd[t] - v; rowptr[i] = ex; cursor[i] = ex; }
        __syncthreads();
        if (t == 0) carry += sd[1023];
        __syncthreads();
    }
    if (t == 0) rowptr[NN] = carry;
}
__global__ void k_scatter(const int* __restrict__ ei, const int* __restrict__ flag,
                          int* __restrict__ cursor, int* __restrict__ csr) {
    int e = blockIdx.x * blockDim.x + threadIdx.x;
    if (e < NE) {
        int mode = *flag;
        int d = ld_idx(ei, NE + e, mode);
        int pos = atomicAdd(&cursor[d], 1);
        csr[pos] = ld_idx(ei, e, mode);
    } else if (e < ET) {
        int n = e - NE;
        int pos = atomicAdd(&cursor[n], 1);
        csr[pos] = n;   // self-loop src == dst
    }
}

// ------- C[M,Ndim] = A[M,K] * W[Ndim,K]^T + bias  (all fp32, fp32 out) -------
__global__ void __launch_bounds__(256) k_gemm_nt(
    const float* __restrict__ A, const float* __restrict__ W,
    const float* __restrict__ bias, float* __restrict__ C,
    int M, int Ndim, int K) {
    __shared__ float As[32][64];
    __shared__ float Ws[32][64];
    int t = threadIdx.x;
    int m0 = blockIdx.x * 64, n0 = blockIdx.y * 64;
    int lm = t >> 2;
    int kc = (t & 3) * 8;
    int tx = t & 15, ty = t >> 4;
    int rowA = m0 + lm;
    int rowW = n0 + lm;
    float acc[4][4] = {};
    for (int kt = 0; kt < K; kt += 32) {
        float av[8];
        if (rowA < M) {
            const float* ap = A + (size_t)rowA * K + kt + kc;
            float4 p0 = *(const float4*)ap;
            float4 p1 = *(const float4*)(ap + 4);
            av[0] = p0.x; av[1] = p0.y; av[2] = p0.z; av[3] = p0.w;
            av[4] = p1.x; av[5] = p1.y; av[6] = p1.z; av[7] = p1.w;
        } else {
            #pragma unroll
            for (int j = 0; j < 8; j++) av[j] = 0.f;
        }
        const float* wp = W + (size_t)rowW * K + kt + kc;
        float4 q0 = *(const float4*)wp;
        float4 q1 = *(const float4*)(wp + 4);
        float wv[8] = {q0.x, q0.y, q0.z, q0.w, q1.x, q1.y, q1.z, q1.w};
        #pragma unroll
        for (int j = 0; j < 8; j++) As[kc + j][lm] = av[j];
        #pragma unroll
        for (int j = 0; j < 8; j++) Ws[kc + j][lm] = wv[j];
        __syncthreads();
        #pragma unroll
        for (int k = 0; k < 32; k++) {
            float4 a4 = *(const float4*)&As[k][ty * 4];
            float4 b4 = *(const float4*)&Ws[k][tx * 4];
            float aa[4] = {a4.x, a4.y, a4.z, a4.w};
            float bb[4] = {b4.x, b4.y, b4.z, b4.w};
            #pragma unroll
            for (int i = 0; i < 4; i++)
                #pragma unroll
                for (int j = 0; j < 4; j++)
                    acc[i][j] = fmaf(aa[i], bb[j], acc[i][j]);
        }
        __syncthreads();
    }
    int col0 = n0 + tx * 4;
    float4 bv = *(const float4*)&bias[col0];
    #pragma unroll
    for (int i = 0; i < 4; i++) {
        int r = m0 + ty * 4 + i;
        if (r < M) {
            float4 o = make_float4(acc[i][0] + bv.x, acc[i][1] + bv.y,
                                   acc[i][2] + bv.z, acc[i][3] + bv.w);
            *(float4*)&C[(size_t)r * Ndim + col0] = o;
        }
    }
}

// ------- fused GATv2 layer 1: one wave per node, online softmax -------
__global__ void __launch_bounds__(256) k_gat1(
    const float* __restrict__ xl, const float* __restrict__ xr,
    const float* __restrict__ att, const float* __restrict__ bias,
    const int* __restrict__ rowptr, const int* __restrict__ csr,
    float* __restrict__ out) {
    int wid = (blockIdx.x * blockDim.x + threadIdx.x) >> 6;
    int lane = threadIdx.x & 63;
    if (wid >= NN) return;
    int n = wid;
    float xrv[HEADS], atv[HEADS], acc[HEADS], lsum[HEADS], mmax[HEADS];
    #pragma unroll
    for (int h = 0; h < HEADS; h++) {
        int c = h * 64 + lane;
        xrv[h] = xr[(size_t)n * 512 + c];
        atv[h] = att[c];
        acc[h] = 0.f; lsum[h] = 0.f; mmax[h] = -1e30f;
    }
    int p0 = rowptr[n], p1 = rowptr[n + 1];
    for (int p = p0; p < p1; p++) {
        int s = csr[p];
        const float* xlrow = xl + (size_t)s * 512;
        float xs[HEADS], sc[HEADS];
        #pragma unroll
        for (int h = 0; h < HEADS; h++) {
            xs[h] = xlrow[h * 64 + lane];
            float v = xs[h] + xrv[h];
            v = (v > 0.f) ? v : NEG * v;
            sc[h] = v * atv[h];
        }
        #pragma unroll
        for (int h = 0; h < HEADS; h++) {
            float ssum = sc[h];
            #pragma unroll
            for (int off = 32; off > 0; off >>= 1)
                ssum += __shfl_xor(ssum, off, 64);
            sc[h] = ssum;
        }
        #pragma unroll
        for (int h = 0; h < HEADS; h++) {
            float mn = fmaxf(mmax[h], sc[h]);
            float scale = __expf(mmax[h] - mn);
            float pe = __expf(sc[h] - mn);
            acc[h] = acc[h] * scale + pe * xs[h];
            lsum[h] = lsum[h] * scale + pe;
            mmax[h] = mn;
        }
    }
    #pragma unroll
    for (int h = 0; h < HEADS; h++) {
        int c = h * 64 + lane;
        float o = acc[h] / (lsum[h] + 1e-16f) + bias[c];
        out[(size_t)n * 512 + c] = (o > 0.f) ? o : 0.f;   // ReLU after layer 1
    }
}

// ------- fused GATv2 layer 2 (1 head, 64 ch): one wave per node -------
__global__ void __launch_bounds__(256) k_gat2(
    const float* __restrict__ xl, const float* __restrict__ xr,
    const float* __restrict__ att, const float* __restrict__ bias,
    const int* __restrict__ rowptr, const int* __restrict__ csr,
    float* __restrict__ out) {
    int wid = (blockIdx.x * blockDim.x + threadIdx.x) >> 6;
    int lane = threadIdx.x & 63;
    if (wid >= NN) return;
    int n = wid;
    float xrv = xr[(size_t)n * 64 + lane];
    float atv = att[lane];
    float acc = 0.f, lsum = 0.f, mmax = -1e30f;
    int p0 = rowptr[n], p1 = rowptr[n + 1];
    for (int p = p0; p < p1; p++) {
        int s = csr[p];
        float xs = xl[(size_t)s * 64 + lane];
        float v = xs + xrv;
        v = (v > 0.f) ? v : NEG * v;
        float sc = v * atv;
        #pragma unroll
        for (int off = 32; off > 0; off >>= 1)
            sc += __shfl_xor(sc, off, 64);
        float mn = fmaxf(mmax, sc);
        float scale = __expf(mmax - mn);
        float pe = __expf(sc - mn);
        acc = acc * scale + pe * xs;
        lsum = lsum * scale + pe;
        mmax = mn;
    }
    float o = acc / (lsum + 1e-16f) + bias[lane];
    out[(size_t)n * 64 + lane] = (o > 0.f) ? o : 0.f;   // ReLU after layer 2
}

// ------- fc_w[5000,64] -> Wt[64][WT_LD] transpose (pad zero-filled) -------
__global__ void __launch_bounds__(256) k_tr(const float* __restrict__ W,
                                            float* __restrict__ Wt) {
    __shared__ float T[64][65];
    int t = threadIdx.x;
    int c0 = blockIdx.x * 64;
    int cl = t >> 2, kq = (t & 3) * 16;
    if (c0 + cl < ODIM) {
        #pragma unroll
        for (int q = 0; q < 4; q++) {
            float4 v = *(const float4*)(W + (size_t)(c0 + cl) * 64 + kq + q * 4);
            T[cl][kq + q * 4 + 0] = v.x;
            T[cl][kq + q * 4 + 1] = v.y;
            T[cl][kq + q * 4 + 2] = v.z;
            T[cl][kq + q * 4 + 3] = v.w;
        }
    } else {
        #pragma unroll
        for (int q = 0; q < 16; q++) T[cl][kq + q] = 0.f;   // zero pad cols
    }
    __syncthreads();
    int kl = t >> 2, cq = (t & 3) * 16;
    #pragma unroll
    for (int q = 0; q < 4; q++) {
        float4 v = make_float4(T[cq + q * 4 + 0][kl], T[cq + q * 4 + 1][kl],
                               T[cq + q * 4 + 2][kl], T[cq + q * 4 + 3][kl]);
        *(float4*)(Wt + (size_t)kl * WT_LD + c0 + cq + q * 4) = v;
    }
}

// --- FC: out[10000,5000] = h2[10000,64] @ Wt + fc_b ---
// block: 8 rows x 1024 cols; thread: 8x4 micro-tile; A-rows staged k-major in
// LDS (k-loop LDS reads are same-address broadcasts = conflict-free); W read
// from L2 with lane-consecutive float4 loads.
__global__ void __launch_bounds__(256) k_fc2(
    const float* __restrict__ A, const float* __restrict__ Wt,
    const float* __restrict__ bias, float* __restrict__ C) {
    __shared__ float As[64][8];
    int t = threadIdx.x;
    int r0 = blockIdx.y * 8;
    int c0 = blockIdx.x * 1024 + t * 4;
    if (t < 128) {
        int r = t >> 4, kq = (t & 15) * 4;
        float4 v = *(const float4*)(A + (size_t)(r0 + r) * 64 + kq);
        As[kq + 0][r] = v.x; As[kq + 1][r] = v.y;
        As[kq + 2][r] = v.z; As[kq + 3][r] = v.w;
    }
    __syncthreads();
    float acc[8][4] = {};
    #pragma unroll 4
    for (int k = 0; k < 64; k++) {
        float4 wv = *(const float4*)(Wt + (size_t)k * WT_LD + c0);
        float4 a0 = *(const float4*)&As[k][0];
        float4 a1 = *(const float4*)&As[k][4];
        float ar[8] = {a0.x, a0.y, a0.z, a0.w, a1.x, a1.y, a1.z, a1.w};
        float wr[4] = {wv.x, wv.y, wv.z, wv.w};
        #pragma unroll
        for (int r = 0; r < 8; r++)
            #pragma unroll
            for (int j = 0; j < 4; j++)
                acc[r][j] = fmaf(ar[r], wr[j], acc[r][j]);
    }
    if (c0 < ODIM) {   // ODIM % 4 == 0: float4 chunk fully valid or fully out
        float4 bv = *(const float4*)(bias + c0);
        #pragma unroll
        for (int r = 0; r < 8; r++) {
            float4 o = make_float4(acc[r][0] + bv.x, acc[r][1] + bv.y,
                                   acc[r][2] + bv.z, acc[r][3] + bv.w);
            *(float4*)&C[(size_t)(r0 + r) * ODIM + c0] = o;
        }
    }
}

extern "C" void kernel_launch(void* const* d_in, const int* in_sizes, int n_in,
                              void* d_out, int out_size, void* d_ws, size_t ws_size,
                              hipStream_t stream) {
    const float* x     = (const float*)d_in[0];
    const int*   ei    = (const int*)d_in[1];
    const float* W1l   = (const float*)d_in[2];
    const float* b1l   = (const float*)d_in[3];
    const float* W1r   = (const float*)d_in[4];
    const float* b1r   = (const float*)d_in[5];
    const float* att1  = (const float*)d_in[6];
    const float* bias1 = (const float*)d_in[7];
    const float* W2l   = (const float*)d_in[8];
    const float* b2l   = (const float*)d_in[9];
    const float* W2r   = (const float*)d_in[10];
    const float* b2r   = (const float*)d_in[11];
    const float* att2  = (const float*)d_in[12];
    const float* bias2 = (const float*)d_in[13];
    const float* fcw   = (const float*)d_in[14];
    const float* fcb   = (const float*)d_in[15];
    float* out = (float*)d_out;

    char* p = (char*)d_ws;
    auto carve = [&](size_t bytes) {
        void* r = (void*)p;
        p += (bytes + 255) & ~(size_t)255;
        return r;
    };
    int* deg    = (int*)carve((size_t)NN * 4);
    int* rowptr = (int*)carve((size_t)(NN + 1) * 4);
    int* cursor = (int*)carve((size_t)NN * 4);
    int* csr    = (int*)carve((size_t)ET * 4);
    int* flag   = (int*)carve(256);
    float* Wt  = (float*)carve((size_t)64 * WT_LD * 4);
    float* xl1 = (float*)carve((size_t)NN * 512 * 4);
    float* xr1 = (float*)carve((size_t)NN * 512 * 4);
    float* h1  = (float*)carve((size_t)NN * 512 * 4);
    float* xl2 = xl1;                            // aliases: xl1/xr1 dead after k_gat1
    float* xr2 = xl1 + (size_t)NN * 64;
    float* h2  = xl1 + (size_t)NN * 128;

    // edge_index layout detection + CSR by destination + fc_w transpose
    k_detect<<<1, 1024, 0, stream>>>(ei, flag);
    k_tr<<<(ODIM + 63) / 64, 256, 0, stream>>>(fcw, Wt);
    k_deg_init<<<(NN + 255) / 256, 256, 0, stream>>>(deg);
    k_hist<<<(NE + 255) / 256, 256, 0, stream>>>(ei, flag, deg);
    k_scan<<<1, 1024, 0, stream>>>(deg, rowptr, cursor);
    k_scatter<<<(ET + 255) / 256, 256, 0, stream>>>(ei, flag, cursor, csr);

    // layer 1
    dim3 g1((NN + 63) / 64, 512 / 64);
    k_gemm_nt<<<g1, 256, 0, stream>>>(x, W1l, b1l, xl1, NN, 512, 512);
    k_gemm_nt<<<g1, 256, 0, stream>>>(x, W1r, b1r, xr1, NN, 512, 512);
    k_gat1<<<(NN * 64 + 255) / 256, 256, 0, stream>>>(xl1, xr1, att1, bias1, rowptr, csr, h1);

    // layer 2
    dim3 g2((NN + 63) / 64, 1);
    k_gemm_nt<<<g2, 256, 0, stream>>>(h1, W2l, b2l, xl2, NN, 64, 512);
    k_gemm_nt<<<g2, 256, 0, stream>>>(h1, W2r, b2r, xr2, NN, 64, 512);
    k_gat2<<<(NN * 64 + 255) / 256, 256, 0, stream>>>(xl2, xr2, att2, bias2, rowptr, csr, h2);

    // FC head: 5 col-blocks x 1250 row-blocks
    dim3 g3((ODIM + 1023) / 1024, NN / 8);
    k_fc2<<<g3, 256, 0, stream>>>(h2, Wt, fcb, out);
}

// Round 6
// 649.317 us; speedup vs baseline: 2.4770x; 1.1221x over previous
//
#include <hip/hip_runtime.h>
#include <hip/hip_bf16.h>

#define NN     10000
#define HEADS  8
#define HID    64
#define ODIM   5000
#define NE     160000
#define ET     170000   // NE + NN self-loops
#define NEG    0.2f
#define WT_LD  5120     // padded leading dim of transposed fc_w

// -------- edge_index storage-format detection (int32 vs int64 words) --------
__global__ void k_detect(const int* __restrict__ ei, int* __restrict__ flag) {
    __shared__ int nz;
    if (threadIdx.x == 0) nz = 0;
    __syncthreads();
    if (ei[2 * threadIdx.x + 1] != 0) atomicAdd(&nz, 1);
    __syncthreads();
    if (threadIdx.x == 0) *flag = (nz == 0) ? 1 : 0;
}
__device__ __forceinline__ int ld_idx(const int* ei, int k, int mode) {
    return mode ? ei[2 * k] : ei[k];   // little-endian lo word carries the id
}

// ---------------- CSR build (by dst) ----------------
__global__ void k_deg_init(int* __restrict__ deg) {
    int i = blockIdx.x * blockDim.x + threadIdx.x;
    if (i < NN) deg[i] = 1;   // self-loop
}
__global__ void k_hist(const int* __restrict__ ei, const int* __restrict__ flag,
                       int* __restrict__ deg) {
    int e = blockIdx.x * blockDim.x + threadIdx.x;
    if (e < NE) atomicAdd(&deg[ld_idx(ei, NE + e, *flag)], 1);
}
__global__ void k_scan(const int* __restrict__ deg, int* __restrict__ rowptr,
                       int* __restrict__ cursor) {
    __shared__ int sd[1024];
    __shared__ int carry;
    int t = threadIdx.x;
    if (t == 0) carry = 0;
    __syncthreads();
    for (int base = 0; base < NN; base += 1024) {
        int i = base + t;
        int v = (i < NN) ? deg[i] : 0;
        sd[t] = v;
        __syncthreads();
        for (int off = 1; off < 1024; off <<= 1) {
            int x = (t >= off) ? sd[t - off] : 0;
            __syncthreads();
            sd[t] += x;
            __syncthreads();
        }
        if (i < NN) { int ex = carry + sd[t] - v; rowptr[i] = ex; cursor[i] = ex; }
        __syncthreads();
        if (t == 0) carry += sd[1023];
        __syncthreads();
    }
    if (t == 0) rowptr[NN] = carry;
}
__global__ void k_scatter(const int* __restrict__ ei, const int* __restrict__ flag,
                          int* __restrict__ cursor, int* __restrict__ csr) {
    int e = blockIdx.x * blockDim.x + threadIdx.x;
    if (e < NE) {
        int mode = *flag;
        int d = ld_idx(ei, NE + e, mode);
        int pos = atomicAdd(&cursor[d], 1);
        csr[pos] = ld_idx(ei, e, mode);
    } else if (e < ET) {
        int n = e - NE;
        int pos = atomicAdd(&cursor[n], 1);
        csr[pos] = n;   // self-loop src == dst
    }
}

// ------- C[M,Ndim] = A[M,K] * W[Ndim,K]^T + bias  (all fp32, fp32 out) -------
__global__ void __launch_bounds__(256) k_gemm_nt(
    const float* __restrict__ A, const float* __restrict__ W,
    const float* __restrict__ bias, float* __restrict__ C,
    int M, int Ndim, int K) {
    __shared__ float As[32][64];
    __shared__ float Ws[32][64];
    int t = threadIdx.x;
    int m0 = blockIdx.x * 64, n0 = blockIdx.y * 64;
    int lm = t >> 2;
    int kc = (t & 3) * 8;
    int tx = t & 15, ty = t >> 4;
    int rowA = m0 + lm;
    int rowW = n0 + lm;
    float acc[4][4] = {};
    for (int kt = 0; kt < K; kt += 32) {
        float av[8];
        if (rowA < M) {
            const float* ap = A + (size_t)rowA * K + kt + kc;
            float4 p0 = *(const float4*)ap;
            float4 p1 = *(const float4*)(ap + 4);
            av[0] = p0.x; av[1] = p0.y; av[2] = p0.z; av[3] = p0.w;
            av[4] = p1.x; av[5] = p1.y; av[6] = p1.z; av[7] = p1.w;
        } else {
            #pragma unroll
            for (int j = 0; j < 8; j++) av[j] = 0.f;
        }
        const float* wp = W + (size_t)rowW * K + kt + kc;
        float4 q0 = *(const float4*)wp;
        float4 q1 = *(const float4*)(wp + 4);
        float wv[8] = {q0.x, q0.y, q0.z, q0.w, q1.x, q1.y, q1.z, q1.w};
        #pragma unroll
        for (int j = 0; j < 8; j++) As[kc + j][lm] = av[j];
        #pragma unroll
        for (int j = 0; j < 8; j++) Ws[kc + j][lm] = wv[j];
        __syncthreads();
        #pragma unroll
        for (int k = 0; k < 32; k++) {
            float4 a4 = *(const float4*)&As[k][ty * 4];
            float4 b4 = *(const float4*)&Ws[k][tx * 4];
            float aa[4] = {a4.x, a4.y, a4.z, a4.w};
            float bb[4] = {b4.x, b4.y, b4.z, b4.w};
            #pragma unroll
            for (int i = 0; i < 4; i++)
                #pragma unroll
                for (int j = 0; j < 4; j++)
                    acc[i][j] = fmaf(aa[i], bb[j], acc[i][j]);
        }
        __syncthreads();
    }
    int col0 = n0 + tx * 4;
    float4 bv = *(const float4*)&bias[col0];
    #pragma unroll
    for (int i = 0; i < 4; i++) {
        int r = m0 + ty * 4 + i;
        if (r < M) {
            float4 o = make_float4(acc[i][0] + bv.x, acc[i][1] + bv.y,
                                   acc[i][2] + bv.z, acc[i][3] + bv.w);
            *(float4*)&C[(size_t)r * Ndim + col0] = o;
        }
    }
}

// ------- fused GATv2 layer 1: one wave per node, online softmax -------
// Lane l = (g=l>>4, q=l&15) owns channels 4q..4q+3 of head g and head g+4.
// Per edge: two coalesced float4 gathers (1KB bursts), 4-ch in-register dot
// partials, 4-step butterfly over the 16-lane group (xor 1,2,4,8), online
// softmax state kept redundantly per group (register-elementwise, free).
__global__ void __launch_bounds__(256) k_gat1(
    const float* __restrict__ xl, const float* __restrict__ xr,
    const float* __restrict__ att, const float* __restrict__ bias,
    const int* __restrict__ rowptr, const int* __restrict__ csr,
    float* __restrict__ out) {
    int wid = (blockIdx.x * blockDim.x + threadIdx.x) >> 6;
    int lane = threadIdx.x & 63;
    if (wid >= NN) return;
    int n = wid;
    int off = lane * 4;            // = (l>>4)*64 + 4*(l&15)
    const float4* xr4  = (const float4*)(xr + (size_t)n * 512 + off);
    const float4* att4 = (const float4*)(att + off);
    float4 xrA = xr4[0],  xrB = xr4[64];    // +256 floats
    float4 atA = att4[0], atB = att4[64];
    float4 accA = make_float4(0.f, 0.f, 0.f, 0.f);
    float4 accB = make_float4(0.f, 0.f, 0.f, 0.f);
    float lA = 0.f, lB = 0.f, mA = -1e30f, mB = -1e30f;

    int p0 = rowptr[n], p1 = rowptr[n + 1];
    int deg = p1 - p0;             // >= 1 (self-loop)
    const float4* xp = (const float4*)(xl + (size_t)csr[p0] * 512 + off);
    float4 xa = xp[0], xb = xp[64];
    for (int i = 0; i < deg; i++) {
        float4 cxa = xa, cxb = xb;
        if (i + 1 < deg) {
            const float4* np = (const float4*)(xl + (size_t)csr[p0 + i + 1] * 512 + off);
            xa = np[0]; xb = np[64];
        }
        // leaky(x+xr) . att, 4-channel partials
        float vA0 = cxa.x + xrA.x, vA1 = cxa.y + xrA.y,
              vA2 = cxa.z + xrA.z, vA3 = cxa.w + xrA.w;
        float vB0 = cxb.x + xrB.x, vB1 = cxb.y + xrB.y,
              vB2 = cxb.z + xrB.z, vB3 = cxb.w + xrB.w;
        vA0 = (vA0 > 0.f) ? vA0 : NEG * vA0;  vA1 = (vA1 > 0.f) ? vA1 : NEG * vA1;
        vA2 = (vA2 > 0.f) ? vA2 : NEG * vA2;  vA3 = (vA3 > 0.f) ? vA3 : NEG * vA3;
        vB0 = (vB0 > 0.f) ? vB0 : NEG * vB0;  vB1 = (vB1 > 0.f) ? vB1 : NEG * vB1;
        vB2 = (vB2 > 0.f) ? vB2 : NEG * vB2;  vB3 = (vB3 > 0.f) ? vB3 : NEG * vB3;
        float sA = vA0 * atA.x + vA1 * atA.y + vA2 * atA.z + vA3 * atA.w;
        float sB = vB0 * atB.x + vB1 * atB.y + vB2 * atB.z + vB3 * atB.w;
        #pragma unroll
        for (int m = 1; m <= 8; m <<= 1) {
            sA += __shfl_xor(sA, m, 64);
            sB += __shfl_xor(sB, m, 64);
        }
        // online softmax update, head A
        float mnA = fmaxf(mA, sA);
        float scA = __expf(mA - mnA), peA = __expf(sA - mnA);
        accA.x = accA.x * scA + peA * cxa.x;  accA.y = accA.y * scA + peA * cxa.y;
        accA.z = accA.z * scA + peA * cxa.z;  accA.w = accA.w * scA + peA * cxa.w;
        lA = lA * scA + peA;  mA = mnA;
        // head B
        float mnB = fmaxf(mB, sB);
        float scB = __expf(mB - mnB), peB = __expf(sB - mnB);
        accB.x = accB.x * scB + peB * cxb.x;  accB.y = accB.y * scB + peB * cxb.y;
        accB.z = accB.z * scB + peB * cxb.z;  accB.w = accB.w * scB + peB * cxb.w;
        lB = lB * scB + peB;  mB = mnB;
    }
    float rA = 1.f / (lA + 1e-16f), rB = 1.f / (lB + 1e-16f);
    float4 biA = *(const float4*)(bias + off);
    float4 biB = *(const float4*)(bias + off + 256);
    float4 oA = make_float4(fmaxf(accA.x * rA + biA.x, 0.f),
                            fmaxf(accA.y * rA + biA.y, 0.f),
                            fmaxf(accA.z * rA + biA.z, 0.f),
                            fmaxf(accA.w * rA + biA.w, 0.f));
    float4 oB = make_float4(fmaxf(accB.x * rB + biB.x, 0.f),
                            fmaxf(accB.y * rB + biB.y, 0.f),
                            fmaxf(accB.z * rB + biB.z, 0.f),
                            fmaxf(accB.w * rB + biB.w, 0.f));
    float4* op = (float4*)(out + (size_t)n * 512 + off);
    op[0]  = oA;      // ReLU applied (layer-1 activation)
    op[64] = oB;
}

// ------- fused GATv2 layer 2 (1 head, 64 ch): one wave per node -------
__global__ void __launch_bounds__(256) k_gat2(
    const float* __restrict__ xl, const float* __restrict__ xr,
    const float* __restrict__ att, const float* __restrict__ bias,
    const int* __restrict__ rowptr, const int* __restrict__ csr,
    float* __restrict__ out) {
    int wid = (blockIdx.x * blockDim.x + threadIdx.x) >> 6;
    int lane = threadIdx.x & 63;
    if (wid >= NN) return;
    int n = wid;
    float xrv = xr[(size_t)n * 64 + lane];
    float atv = att[lane];
    float acc = 0.f, lsum = 0.f, mmax = -1e30f;
    int p0 = rowptr[n], p1 = rowptr[n + 1];
    for (int p = p0; p < p1; p++) {
        int s = csr[p];
        float xs = xl[(size_t)s * 64 + lane];
        float v = xs + xrv;
        v = (v > 0.f) ? v : NEG * v;
        float sc = v * atv;
        #pragma unroll
        for (int off = 32; off > 0; off >>= 1)
            sc += __shfl_xor(sc, off, 64);
        float mn = fmaxf(mmax, sc);
        float scale = __expf(mmax - mn);
        float pe = __expf(sc - mn);
        acc = acc * scale + pe * xs;
        lsum = lsum * scale + pe;
        mmax = mn;
    }
    float o = acc / (lsum + 1e-16f) + bias[lane];
    out[(size_t)n * 64 + lane] = (o > 0.f) ? o : 0.f;   // ReLU after layer 2
}

// ------- fc_w[5000,64] -> Wt[64][WT_LD] transpose (pad zero-filled) -------
__global__ void __launch_bounds__(256) k_tr(const float* __restrict__ W,
                                            float* __restrict__ Wt) {
    __shared__ float T[64][65];
    int t = threadIdx.x;
    int c0 = blockIdx.x * 64;
    int cl = t >> 2, kq = (t & 3) * 16;
    if (c0 + cl < ODIM) {
        #pragma unroll
        for (int q = 0; q < 4; q++) {
            float4 v = *(const float4*)(W + (size_t)(c0 + cl) * 64 + kq + q * 4);
            T[cl][kq + q * 4 + 0] = v.x;
            T[cl][kq + q * 4 + 1] = v.y;
            T[cl][kq + q * 4 + 2] = v.z;
            T[cl][kq + q * 4 + 3] = v.w;
        }
    } else {
        #pragma unroll
        for (int q = 0; q < 16; q++) T[cl][kq + q] = 0.f;   // zero pad cols
    }
    __syncthreads();
    int kl = t >> 2, cq = (t & 3) * 16;
    #pragma unroll
    for (int q = 0; q < 4; q++) {
        float4 v = make_float4(T[cq + q * 4 + 0][kl], T[cq + q * 4 + 1][kl],
                               T[cq + q * 4 + 2][kl], T[cq + q * 4 + 3][kl]);
        *(float4*)(Wt + (size_t)kl * WT_LD + c0 + cq + q * 4) = v;
    }
}

// --- FC: out[10000,5000] = h2[10000,64] @ Wt + fc_b ---
__global__ void __launch_bounds__(256) k_fc2(
    const float* __restrict__ A, const float* __restrict__ Wt,
    const float* __restrict__ bias, float* __restrict__ C) {
    __shared__ float As[64][8];
    int t = threadIdx.x;
    int r0 = blockIdx.y * 8;
    int c0 = blockIdx.x * 1024 + t * 4;
    if (t < 128) {
        int r = t >> 4, kq = (t & 15) * 4;
        float4 v = *(const float4*)(A + (size_t)(r0 + r) * 64 + kq);
        As[kq + 0][r] = v.x; As[kq + 1][r] = v.y;
        As[kq + 2][r] = v.z; As[kq + 3][r] = v.w;
    }
    __syncthreads();
    float acc[8][4] = {};
    #pragma unroll 4
    for (int k = 0; k < 64; k++) {
        float4 wv = *(const float4*)(Wt + (size_t)k * WT_LD + c0);
        float4 a0 = *(const float4*)&As[k][0];
        float4 a1 = *(const float4*)&As[k][4];
        float ar[8] = {a0.x, a0.y, a0.z, a0.w, a1.x, a1.y, a1.z, a1.w};
        float wr[4] = {wv.x, wv.y, wv.z, wv.w};
        #pragma unroll
        for (int r = 0; r < 8; r++)
            #pragma unroll
            for (int j = 0; j < 4; j++)
                acc[r][j] = fmaf(ar[r], wr[j], acc[r][j]);
    }
    if (c0 < ODIM) {   // ODIM % 4 == 0: float4 chunk fully valid or fully out
        float4 bv = *(const float4*)(bias + c0);
        #pragma unroll
        for (int r = 0; r < 8; r++) {
            float4 o = make_float4(acc[r][0] + bv.x, acc[r][1] + bv.y,
                                   acc[r][2] + bv.z, acc[r][3] + bv.w);
            *(float4*)&C[(size_t)(r0 + r) * ODIM + c0] = o;
        }
    }
}

extern "C" void kernel_launch(void* const* d_in, const int* in_sizes, int n_in,
                              void* d_out, int out_size, void* d_ws, size_t ws_size,
                              hipStream_t stream) {
    const float* x     = (const float*)d_in[0];
    const int*   ei    = (const int*)d_in[1];
    const float* W1l   = (const float*)d_in[2];
    const float* b1l   = (const float*)d_in[3];
    const float* W1r   = (const float*)d_in[4];
    const float* b1r   = (const float*)d_in[5];
    const float* att1  = (const float*)d_in[6];
    const float* bias1 = (const float*)d_in[7];
    const float* W2l   = (const float*)d_in[8];
    const float* b2l   = (const float*)d_in[9];
    const float* W2r   = (const float*)d_in[10];
    const float* b2r   = (const float*)d_in[11];
    const float* att2  = (const float*)d_in[12];
    const float* bias2 = (const float*)d_in[13];
    const float* fcw   = (const float*)d_in[14];
    const float* fcb   = (const float*)d_in[15];
    float* out = (float*)d_out;

    char* p = (char*)d_ws;
    auto carve = [&](size_t bytes) {
        void* r = (void*)p;
        p += (bytes + 255) & ~(size_t)255;
        return r;
    };
    int* deg    = (int*)carve((size_t)NN * 4);
    int* rowptr = (int*)carve((size_t)(NN + 1) * 4);
    int* cursor = (int*)carve((size_t)NN * 4);
    int* csr    = (int*)carve((size_t)ET * 4);
    int* flag   = (int*)carve(256);
    float* Wt  = (float*)carve((size_t)64 * WT_LD * 4);
    float* xl1 = (float*)carve((size_t)NN * 512 * 4);
    float* xr1 = (float*)carve((size_t)NN * 512 * 4);
    float* h1  = (float*)carve((size_t)NN * 512 * 4);
    float* xl2 = xl1;                            // aliases: xl1/xr1 dead after k_gat1
    float* xr2 = xl1 + (size_t)NN * 64;
    float* h2  = xl1 + (size_t)NN * 128;

    // edge_index layout detection + CSR by destination + fc_w transpose
    k_detect<<<1, 1024, 0, stream>>>(ei, flag);
    k_tr<<<(ODIM + 63) / 64, 256, 0, stream>>>(fcw, Wt);
    k_deg_init<<<(NN + 255) / 256, 256, 0, stream>>>(deg);
    k_hist<<<(NE + 255) / 256, 256, 0, stream>>>(ei, flag, deg);
    k_scan<<<1, 1024, 0, stream>>>(deg, rowptr, cursor);
    k_scatter<<<(ET + 255) / 256, 256, 0, stream>>>(ei, flag, cursor, csr);

    // layer 1
    dim3 g1((NN + 63) / 64, 512 / 64);
    k_gemm_nt<<<g1, 256, 0, stream>>>(x, W1l, b1l, xl1, NN, 512, 512);
    k_gemm_nt<<<g1, 256, 0, stream>>>(x, W1r, b1r, xr1, NN, 512, 512);
    k_gat1<<<(NN * 64 + 255) / 256, 256, 0, stream>>>(xl1, xr1, att1, bias1, rowptr, csr, h1);

    // layer 2
    dim3 g2((NN + 63) / 64, 1);
    k_gemm_nt<<<g2, 256, 0, stream>>>(h1, W2l, b2l, xl2, NN, 64, 512);
    k_gemm_nt<<<g2, 256, 0, stream>>>(h1, W2r, b2r, xr2, NN, 64, 512);
    k_gat2<<<(NN * 64 + 255) / 256, 256, 0, stream>>>(xl2, xr2, att2, bias2, rowptr, csr, h2);

    // FC head: 5 col-blocks x 1250 row-blocks
    dim3 g3((ODIM + 1023) / 1024, NN / 8);
    k_fc2<<<g3, 256, 0, stream>>>(h2, Wt, fcb, out);
}